// Round 4
// baseline (112.304 us; speedup 1.0000x reference)
//
#include <hip/hip_runtime.h>
#include <hip/hip_bf16.h>

#define B_ 8
#define Q_ 128
#define K_ 256
#define D_ 512
#define TWOLOG2E 2.8853900817779268f
#define SCALE 0.044194173824159216f   // 1/sqrt(512)
#define L2E 1.4426950408889634f
#define MASKVAL (-44194173.824159216f) // -1e9 * SCALE

typedef __attribute__((ext_vector_type(8))) short frag8;   // 8 bf16
typedef __attribute__((ext_vector_type(4))) float f32x4;

__device__ __forceinline__ float fexp2(float x) {
  float r;
  asm("v_exp_f32 %0, %1" : "=v"(r) : "v"(x));
  return r;
}
__device__ __forceinline__ float frcp(float x) {
  float r;
  asm("v_rcp_f32 %0, %1" : "=v"(r) : "v"(x));
  return r;
}
__device__ __forceinline__ unsigned f2bf_u(float x) {
  unsigned u = __float_as_uint(x);
  return (u + 0x7FFFu + ((u >> 16) & 1u)) >> 16;
}
__device__ __forceinline__ unsigned short f2bf(float x) {
  return (unsigned short)f2bf_u(x);
}
__device__ __forceinline__ unsigned packbf(float lo, float hi) {
  return f2bf_u(lo) | (f2bf_u(hi) << 16);
}

// ---------------- Kernel 1: fused convert + MFMA projection GEMM ----------------
// (unchanged)
__global__ __launch_bounds__(256) void gemm_kernel(
    const float* __restrict__ query, const float* __restrict__ key,
    const float* __restrict__ W1, const float* __restrict__ b1,
    float* __restrict__ qp, float* __restrict__ kpbT) {
  __shared__ short As[32 * 64];
  __shared__ short Bs[64 * 72];
  const int t = threadIdx.x;
  const int m0 = blockIdx.y * 32;
  const int n0 = blockIdx.x * 64;
  const bool is_k = (m0 >= B_ * Q_);
  const float* X = is_k ? key : query;
  const int xrow0 = is_k ? (m0 - B_ * Q_) : m0;
  const float* Wb = W1 + (is_k ? (size_t)D_ * D_ : 0);

  const int am = t >> 3;
  const int ac = t & 7;
  const float* gA = X + (size_t)(xrow0 + am) * D_ + ac * 8;
  short* aw = As + am * 64 + ((ac ^ (am & 7)) * 8);

  const int prow = t >> 4;
  const int n4 = (t & 15) * 4;
  const float* gB = Wb + n0 + n4;

  const int l = t & 63;
  const int w = t >> 6;
  const int lr = l & 15;
  const int kg = l >> 4;
  const int key8 = lr & 7;
  int aoff[2][2], boff[2];
#pragma unroll
  for (int kk = 0; kk < 2; ++kk) {
    const int cposA = ((kg + kk * 4) ^ key8) * 8;
#pragma unroll
    for (int mt = 0; mt < 2; ++mt) aoff[mt][kk] = (mt * 16 + lr) * 64 + cposA;
    boff[kk] = (w * 16 + lr) * 72 + (kg + kk * 4) * 8;
  }

  f32x4 acc[2];
  acc[0] = (f32x4){0.f, 0.f, 0.f, 0.f};
  acc[1] = (f32x4){0.f, 0.f, 0.f, 0.f};

  for (int k0 = 0; k0 < D_; k0 += 64) {
    float4 a0 = *(const float4*)(gA + k0);
    float4 a1 = *(const float4*)(gA + k0 + 4);
    float4 w00 = *(const float4*)(gB + (size_t)(k0 + 2 * prow) * D_);
    float4 w01 = *(const float4*)(gB + (size_t)(k0 + 2 * prow + 1) * D_);
    float4 w10 = *(const float4*)(gB + (size_t)(k0 + 2 * prow + 32) * D_);
    float4 w11 = *(const float4*)(gB + (size_t)(k0 + 2 * prow + 33) * D_);
    __syncthreads();
    {
      union { frag8 f; unsigned short u[8]; } av;
      av.u[0] = f2bf(a0.x); av.u[1] = f2bf(a0.y); av.u[2] = f2bf(a0.z); av.u[3] = f2bf(a0.w);
      av.u[4] = f2bf(a1.x); av.u[5] = f2bf(a1.y); av.u[6] = f2bf(a1.z); av.u[7] = f2bf(a1.w);
      *(frag8*)aw = av.f;
    }
    {
      float lo0[4] = {w00.x, w00.y, w00.z, w00.w};
      float hi0[4] = {w01.x, w01.y, w01.z, w01.w};
      float lo1[4] = {w10.x, w10.y, w10.z, w10.w};
      float hi1[4] = {w11.x, w11.y, w11.z, w11.w};
#pragma unroll
      for (int j = 0; j < 4; ++j) {
        *(unsigned*)(Bs + (n4 + j) * 72 + 2 * prow) = packbf(lo0[j], hi0[j]);
        *(unsigned*)(Bs + (n4 + j) * 72 + 2 * (prow + 16)) = packbf(lo1[j], hi1[j]);
      }
    }
    __syncthreads();
#pragma unroll
    for (int kk = 0; kk < 2; ++kk) {
      frag8 bf = *(const frag8*)(Bs + boff[kk]);
#pragma unroll
      for (int mt = 0; mt < 2; ++mt) {
        frag8 af = *(const frag8*)(As + aoff[mt][kk]);
        acc[mt] = __builtin_amdgcn_mfma_f32_16x16x32_bf16(af, bf, acc[mt], 0, 0, 0);
      }
    }
  }

  const int col = n0 + w * 16 + lr;
  if (is_k) {
    const float bc = b1[col];
#pragma unroll
    for (int mt = 0; mt < 2; ++mt) {
      const int krow = m0 - B_ * Q_ + mt * 16 + kg * 4;
      const int bb = krow >> 8;
      const int kk0 = krow & 255;
      float4 v;
      v.x = fexp2((acc[mt][0] + bc) * TWOLOG2E);
      v.y = fexp2((acc[mt][1] + bc) * TWOLOG2E);
      v.z = fexp2((acc[mt][2] + bc) * TWOLOG2E);
      v.w = fexp2((acc[mt][3] + bc) * TWOLOG2E);
      *(float4*)&kpbT[((size_t)bb * D_ + col) * K_ + kk0] = v;
    }
  } else {
#pragma unroll
    for (int mt = 0; mt < 2; ++mt) {
#pragma unroll
      for (int i = 0; i < 4; ++i) {
        const int row = m0 + mt * 16 + kg * 4 + i;
        qp[(size_t)row * D_ + col] = fexp2(acc[mt][i] * TWOLOG2E);
      }
    }
  }
}

// ---------------- Kernel 2: fused tanh-score + softmax + PV ----------------
// qp holds Eq = e^{2 qproj}; kpbT holds Ek = e^{2(kproj+b1)}.
// 1024 threads = 16 waves, 4 q-rows/block, 1-D grid of 256 blocks.
// XCD swizzle: b = bid & 7.
// MASK COMPACTION: ~half of k are masked (weight exactly 0). Wave 0 ballot-
// compacts unmasked k indices into ck[0..nk). Phase 1 runs 16 h-chunks of 32;
// each wave covers compacted positions in npass = ceil(nk/64) passes (wave-
// uniform dynamic trip count: 4 dense -> typically 2-3), cutting the dominant
// VALU phase by ~25-50%. 2-way rcp pairing along h retained.
__global__ __launch_bounds__(1024) void attn_kernel(
    const float* __restrict__ qp, const float* __restrict__ kpbT,
    const float* __restrict__ value, const int* __restrict__ mask,
    const float* __restrict__ w2,
    float* __restrict__ out_vec, float* __restrict__ out_w) {
  __shared__ float smem_p[16 * 4 * 256];  // phase1: [w][q][pos] 64 KB; phase3: [kq][q][col]
  __shared__ float pw[4 * 256];           // dense final weights [q][k]  4 KB
  __shared__ int ck[K_];                  // compacted unmasked k indices
  __shared__ int nk_sh;
  const int bid = blockIdx.x;
  const int b = bid & 7;               // XCD-local batch
  const int q0 = (bid >> 3) * 4;       // q-chunk
  const int t = threadIdx.x;
  const int lane = t & 63;
  const int w = __builtin_amdgcn_readfirstlane(t >> 6);  // 0..15

  // ---- phase 0: ballot-compaction of unmasked k (wave 0)
  if (t < 64) {
    int base = 0;
#pragma unroll
    for (int r = 0; r < 4; ++r) {
      const int k = r * 64 + lane;
      const bool um = (mask[b * K_ + k] == 0);
      const unsigned long long bal = __ballot(um);
      if (um) ck[base + __popcll(bal & ((1ull << lane) - 1ull))] = k;
      base += (int)__popcll(bal);
    }
    if (lane == 0) nk_sh = base;
  }
  __syncthreads();
  const int nk = nk_sh;
  const int npass = (nk + 63) >> 6;  // wave-uniform (block-uniform)

  // ---- phase 1: wave w covers h-range [w*32, w*32+32), compacted k in passes
  {
    const int h0p = w * 32;
    const float* pkrow = kpbT + ((size_t)b * D_ + h0p) * K_;
    const float* q_0 = qp + (size_t)(b * Q_ + q0 + 0) * D_ + h0p;
    const float* q_1 = qp + (size_t)(b * Q_ + q0 + 1) * D_ + h0p;
    const float* q_2 = qp + (size_t)(b * Q_ + q0 + 2) * D_ + h0p;
    const float* q_3 = qp + (size_t)(b * Q_ + q0 + 3) * D_ + h0p;
    const float* w2h = w2 + h0p;

    int kidx[4];
#pragma unroll
    for (int p = 0; p < 4; ++p) {
      const int pos = p * 64 + lane;
      kidx[p] = (pos < nk) ? ck[pos] : 0;  // clamped: garbage lanes compute finite junk
    }

    float acc[4][4];  // [pass][q] — statically indexed via full unroll
#pragma unroll
    for (int p = 0; p < 4; ++p)
#pragma unroll
      for (int qi = 0; qi < 4; ++qi) acc[p][qi] = 0.f;

    for (int h = 0; h < 32; h += 2) {
      const float2 wv = *(const float2*)(w2h + h);   // wave-uniform broadcasts
      const float2 e0 = *(const float2*)(q_0 + h);
      const float2 e1 = *(const float2*)(q_1 + h);
      const float2 e2 = *(const float2*)(q_2 + h);
      const float2 e3 = *(const float2*)(q_3 + h);
      const float* ra = pkrow + (size_t)h * K_;
      const float* rb = ra + K_;
#pragma unroll
      for (int p = 0; p < 4; ++p) {
        if (p < npass) {  // wave-uniform guard; p compile-time after unroll
          const float eka = ra[kidx[p]];  // per-lane gather (L2-resident)
          const float ekb = rb[kidx[p]];
          {
            const float da = fmaf(e0.x, eka, 1.f), db = fmaf(e0.y, ekb, 1.f);
            acc[p][0] = fmaf(fmaf(wv.x, db, wv.y * da), frcp(da * db), acc[p][0]);
          }
          {
            const float da = fmaf(e1.x, eka, 1.f), db = fmaf(e1.y, ekb, 1.f);
            acc[p][1] = fmaf(fmaf(wv.x, db, wv.y * da), frcp(da * db), acc[p][1]);
          }
          {
            const float da = fmaf(e2.x, eka, 1.f), db = fmaf(e2.y, ekb, 1.f);
            acc[p][2] = fmaf(fmaf(wv.x, db, wv.y * da), frcp(da * db), acc[p][2]);
          }
          {
            const float da = fmaf(e3.x, eka, 1.f), db = fmaf(e3.y, ekb, 1.f);
            acc[p][3] = fmaf(fmaf(wv.x, db, wv.y * da), frcp(da * db), acc[p][3]);
          }
        }
      }
    }
#pragma unroll
    for (int p = 0; p < 4; ++p) {
      if (p < npass) {
#pragma unroll
        for (int qi = 0; qi < 4; ++qi)
          smem_p[(w * 4 + qi) * 256 + p * 64 + lane] = acc[p][qi];
      }
    }
  }
  __syncthreads();

  // ---- phase 2: combine 16 h-chunks + softmax over compacted set; wave q row
  if (w < 4) {
    const int q = w;
    float sw = 0.f;
#pragma unroll
    for (int m = 0; m < 8; ++m) sw += w2[lane + 64 * m];
#pragma unroll
    for (int off = 32; off; off >>= 1) sw += __shfl_xor(sw, off);

    float s[4];
#pragma unroll
    for (int r = 0; r < 4; ++r) {  // compacted position pos = r*64 + lane
      const int pos = r * 64 + lane;
      float p = 0.f;
#pragma unroll
      for (int wv = 0; wv < 16; ++wv) p += smem_p[(wv * 4 + q) * 256 + pos];
      s[r] = (pos < nk) ? fmaf(-2.f, p, sw) * SCALE : MASKVAL;
    }
    float mx = fmaxf(fmaxf(s[0], s[1]), fmaxf(s[2], s[3]));
#pragma unroll
    for (int off = 32; off; off >>= 1) mx = fmaxf(mx, __shfl_xor(mx, off));
    float e[4], sum = 0.f;
#pragma unroll
    for (int r = 0; r < 4; ++r) {
      e[r] = fexp2((s[r] - mx) * L2E);  // invalid pos -> exp2(very neg) = 0
      sum += e[r];
    }
#pragma unroll
    for (int off = 32; off; off >>= 1) sum += __shfl_xor(sum, off);
    const float inv = frcp(sum);
    // dense zero, then scatter through ck (same-wave LDS ops are ordered)
#pragma unroll
    for (int r = 0; r < 4; ++r) pw[q * 256 + r * 64 + lane] = 0.f;
#pragma unroll
    for (int r = 0; r < 4; ++r) {
      const int pos = r * 64 + lane;
      if (pos < nk) pw[q * 256 + ck[pos]] = e[r] * inv;
    }
    float* ow = out_w + (size_t)(b * Q_ + q0 + q) * K_;
#pragma unroll
    for (int r = 0; r < 4; ++r) ow[r * 64 + lane] = pw[q * 256 + r * 64 + lane];
  }
  __syncthreads();

  // ---- phase 3: PV, k-split (unchanged).
  // thread t: col pair, cp = t&255; k-quarter kq = t>>8 (wave-uniform).
  {
    const int cp = t & 255;
    const int col = cp * 2;
    const int kq = t >> 8;  // 0..3, constant within a wave
    const float* vb = value + (size_t)b * K_ * D_ + (size_t)(kq * 64) * D_ + col;
    const float* pwq = pw + kq * 64;

    float2 o0 = {0.f, 0.f}, o1 = {0.f, 0.f}, o2 = {0.f, 0.f}, o3 = {0.f, 0.f};
    for (int k0 = 0; k0 < 64; k0 += 4) {
      const float4 P0 = *(const float4*)&pwq[0 * 256 + k0];  // ds_read_b128, broadcast
      const float4 P1 = *(const float4*)&pwq[1 * 256 + k0];
      const float4 P2 = *(const float4*)&pwq[2 * 256 + k0];
      const float4 P3 = *(const float4*)&pwq[3 * 256 + k0];
      const float2 v0 = *(const float2*)&vb[(size_t)(k0 + 0) * D_];
      const float2 v1 = *(const float2*)&vb[(size_t)(k0 + 1) * D_];
      const float2 v2 = *(const float2*)&vb[(size_t)(k0 + 2) * D_];
      const float2 v3 = *(const float2*)&vb[(size_t)(k0 + 3) * D_];
      o0.x = fmaf(P0.x, v0.x, fmaf(P0.y, v1.x, fmaf(P0.z, v2.x, fmaf(P0.w, v3.x, o0.x))));
      o0.y = fmaf(P0.x, v0.y, fmaf(P0.y, v1.y, fmaf(P0.z, v2.y, fmaf(P0.w, v3.y, o0.y))));
      o1.x = fmaf(P1.x, v0.x, fmaf(P1.y, v1.x, fmaf(P1.z, v2.x, fmaf(P1.w, v3.x, o1.x))));
      o1.y = fmaf(P1.x, v0.y, fmaf(P1.y, v1.y, fmaf(P1.z, v2.y, fmaf(P1.w, v3.y, o1.y))));
      o2.x = fmaf(P2.x, v0.x, fmaf(P2.y, v1.x, fmaf(P2.z, v2.x, fmaf(P2.w, v3.x, o2.x))));
      o2.y = fmaf(P2.x, v0.y, fmaf(P2.y, v1.y, fmaf(P2.z, v2.y, fmaf(P2.w, v3.y, o2.y))));
      o3.x = fmaf(P3.x, v0.x, fmaf(P3.y, v1.x, fmaf(P3.z, v2.x, fmaf(P3.w, v3.x, o3.x))));
      o3.y = fmaf(P3.x, v0.y, fmaf(P3.y, v1.y, fmaf(P3.z, v2.y, fmaf(P3.w, v3.y, o3.y))));
    }
    __syncthreads();  // phase-2 smem_p reads done; safe to overwrite
    // partial layout: smem_p[kq][q][col] = kq*2048 + q*512 + col
    *(float2*)&smem_p[kq * 2048 + 0 * 512 + col] = o0;
    *(float2*)&smem_p[kq * 2048 + 1 * 512 + col] = o1;
    *(float2*)&smem_p[kq * 2048 + 2 * 512 + col] = o2;
    *(float2*)&smem_p[kq * 2048 + 3 * 512 + col] = o3;
  }
  __syncthreads();

  // ---- final reduce: 2048 outputs (4 q x 512 col), 2 per thread
  {
#pragma unroll
    for (int rep = 0; rep < 2; ++rep) {
      const int idx = t + rep * 1024;
      const int q = idx >> 9;
      const int c = idx & 511;
      const float s = smem_p[0 * 2048 + q * 512 + c] + smem_p[1 * 2048 + q * 512 + c] +
                      smem_p[2 * 2048 + q * 512 + c] + smem_p[3 * 2048 + q * 512 + c];
      out_vec[(size_t)(b * Q_ + q0 + q) * D_ + c] = s;
    }
  }
}

extern "C" void kernel_launch(void* const* d_in, const int* in_sizes, int n_in,
                              void* d_out, int out_size, void* d_ws, size_t ws_size,
                              hipStream_t stream) {
  const float* query = (const float*)d_in[0];
  const float* key   = (const float*)d_in[1];
  const float* value = (const float*)d_in[2];
  const int*   mask  = (const int*)d_in[3];
  const float* W1    = (const float*)d_in[4];
  const float* b1    = (const float*)d_in[5];
  const float* w2    = (const float*)d_in[6];

  float* out_vec = (float*)d_out;                   // (8,128,512)
  float* out_w   = out_vec + (size_t)B_ * Q_ * D_;  // (8,128,256)

  float* qp   = (float*)d_ws;                       // 2 MB fp32 Eq [b][q][h]
  float* kpbT = qp + (size_t)B_ * Q_ * D_;          // 4 MB fp32 Ek [b][h][k]

  gemm_kernel<<<dim3(8, 96), 256, 0, stream>>>(query, key, W1, b1, qp, kpbT);
  attn_kernel<<<dim3(256), 1024, 0, stream>>>(qp, kpbT, value, mask, w2,
                                              out_vec, out_w);
}

// Round 5
// 106.229 us; speedup vs baseline: 1.0572x; 1.0572x over previous
//
#include <hip/hip_runtime.h>
#include <hip/hip_bf16.h>

#define B_ 8
#define Q_ 128
#define K_ 256
#define D_ 512
#define TWOLOG2E 2.8853900817779268f
#define SCALE 0.044194173824159216f   // 1/sqrt(512)
#define L2E 1.4426950408889634f
#define MASKVAL (-44194173.824159216f) // -1e9 * SCALE

typedef __attribute__((ext_vector_type(8))) short frag8;   // 8 bf16
typedef __attribute__((ext_vector_type(4))) float f32x4;

__device__ __forceinline__ float fexp2(float x) {
  float r;
  asm("v_exp_f32 %0, %1" : "=v"(r) : "v"(x));
  return r;
}
__device__ __forceinline__ float frcp(float x) {
  float r;
  asm("v_rcp_f32 %0, %1" : "=v"(r) : "v"(x));
  return r;
}
__device__ __forceinline__ unsigned f2bf_u(float x) {
  unsigned u = __float_as_uint(x);
  return (u + 0x7FFFu + ((u >> 16) & 1u)) >> 16;
}
__device__ __forceinline__ unsigned short f2bf(float x) {
  return (unsigned short)f2bf_u(x);
}
__device__ __forceinline__ unsigned packbf(float lo, float hi) {
  return f2bf_u(lo) | (f2bf_u(hi) << 16);
}

// 8-way rcp pairing: sum_{j=0..7} w[j]/d[j] with ONE v_rcp.
// d[j] = 1 + E[j]*Kv[j] >= 1 (no zero/denormal risk).
// Overflow of prod(d) needs ~10-sigma inputs -> negligible.
__device__ __forceinline__ float oct_term(const float* __restrict__ E,
                                          const float* __restrict__ Kv,
                                          const float* __restrict__ Wv) {
  float d[8];
#pragma unroll
  for (int j = 0; j < 8; ++j) d[j] = fmaf(E[j], Kv[j], 1.f);
  const float d01 = d[0] * d[1], d23 = d[2] * d[3];
  const float d45 = d[4] * d[5], d67 = d[6] * d[7];
  const float n01 = fmaf(Wv[0], d[1], Wv[1] * d[0]);
  const float n23 = fmaf(Wv[2], d[3], Wv[3] * d[2]);
  const float n45 = fmaf(Wv[4], d[5], Wv[5] * d[4]);
  const float n67 = fmaf(Wv[6], d[7], Wv[7] * d[6]);
  const float d0123 = d01 * d23, d4567 = d45 * d67;
  const float n0123 = fmaf(n01, d23, n23 * d01);
  const float n4567 = fmaf(n45, d67, n67 * d45);
  const float num = fmaf(n0123, d4567, n4567 * d0123);
  return num * frcp(d0123 * d4567);
}

// ---------------- Kernel 1: fused convert + MFMA projection GEMM ----------------
// (unchanged)
__global__ __launch_bounds__(256) void gemm_kernel(
    const float* __restrict__ query, const float* __restrict__ key,
    const float* __restrict__ W1, const float* __restrict__ b1,
    float* __restrict__ qp, float* __restrict__ kpbT) {
  __shared__ short As[32 * 64];
  __shared__ short Bs[64 * 72];
  const int t = threadIdx.x;
  const int m0 = blockIdx.y * 32;
  const int n0 = blockIdx.x * 64;
  const bool is_k = (m0 >= B_ * Q_);
  const float* X = is_k ? key : query;
  const int xrow0 = is_k ? (m0 - B_ * Q_) : m0;
  const float* Wb = W1 + (is_k ? (size_t)D_ * D_ : 0);

  const int am = t >> 3;
  const int ac = t & 7;
  const float* gA = X + (size_t)(xrow0 + am) * D_ + ac * 8;
  short* aw = As + am * 64 + ((ac ^ (am & 7)) * 8);

  const int prow = t >> 4;
  const int n4 = (t & 15) * 4;
  const float* gB = Wb + n0 + n4;

  const int l = t & 63;
  const int w = t >> 6;
  const int lr = l & 15;
  const int kg = l >> 4;
  const int key8 = lr & 7;
  int aoff[2][2], boff[2];
#pragma unroll
  for (int kk = 0; kk < 2; ++kk) {
    const int cposA = ((kg + kk * 4) ^ key8) * 8;
#pragma unroll
    for (int mt = 0; mt < 2; ++mt) aoff[mt][kk] = (mt * 16 + lr) * 64 + cposA;
    boff[kk] = (w * 16 + lr) * 72 + (kg + kk * 4) * 8;
  }

  f32x4 acc[2];
  acc[0] = (f32x4){0.f, 0.f, 0.f, 0.f};
  acc[1] = (f32x4){0.f, 0.f, 0.f, 0.f};

  for (int k0 = 0; k0 < D_; k0 += 64) {
    float4 a0 = *(const float4*)(gA + k0);
    float4 a1 = *(const float4*)(gA + k0 + 4);
    float4 w00 = *(const float4*)(gB + (size_t)(k0 + 2 * prow) * D_);
    float4 w01 = *(const float4*)(gB + (size_t)(k0 + 2 * prow + 1) * D_);
    float4 w10 = *(const float4*)(gB + (size_t)(k0 + 2 * prow + 32) * D_);
    float4 w11 = *(const float4*)(gB + (size_t)(k0 + 2 * prow + 33) * D_);
    __syncthreads();
    {
      union { frag8 f; unsigned short u[8]; } av;
      av.u[0] = f2bf(a0.x); av.u[1] = f2bf(a0.y); av.u[2] = f2bf(a0.z); av.u[3] = f2bf(a0.w);
      av.u[4] = f2bf(a1.x); av.u[5] = f2bf(a1.y); av.u[6] = f2bf(a1.z); av.u[7] = f2bf(a1.w);
      *(frag8*)aw = av.f;
    }
    {
      float lo0[4] = {w00.x, w00.y, w00.z, w00.w};
      float hi0[4] = {w01.x, w01.y, w01.z, w01.w};
      float lo1[4] = {w10.x, w10.y, w10.z, w10.w};
      float hi1[4] = {w11.x, w11.y, w11.z, w11.w};
#pragma unroll
      for (int j = 0; j < 4; ++j) {
        *(unsigned*)(Bs + (n4 + j) * 72 + 2 * prow) = packbf(lo0[j], hi0[j]);
        *(unsigned*)(Bs + (n4 + j) * 72 + 2 * (prow + 16)) = packbf(lo1[j], hi1[j]);
      }
    }
    __syncthreads();
#pragma unroll
    for (int kk = 0; kk < 2; ++kk) {
      frag8 bf = *(const frag8*)(Bs + boff[kk]);
#pragma unroll
      for (int mt = 0; mt < 2; ++mt) {
        frag8 af = *(const frag8*)(As + aoff[mt][kk]);
        acc[mt] = __builtin_amdgcn_mfma_f32_16x16x32_bf16(af, bf, acc[mt], 0, 0, 0);
      }
    }
  }

  const int col = n0 + w * 16 + lr;
  if (is_k) {
    const float bc = b1[col];
#pragma unroll
    for (int mt = 0; mt < 2; ++mt) {
      const int krow = m0 - B_ * Q_ + mt * 16 + kg * 4;
      const int bb = krow >> 8;
      const int kk0 = krow & 255;
      float4 v;
      v.x = fexp2((acc[mt][0] + bc) * TWOLOG2E);
      v.y = fexp2((acc[mt][1] + bc) * TWOLOG2E);
      v.z = fexp2((acc[mt][2] + bc) * TWOLOG2E);
      v.w = fexp2((acc[mt][3] + bc) * TWOLOG2E);
      *(float4*)&kpbT[((size_t)bb * D_ + col) * K_ + kk0] = v;
    }
  } else {
#pragma unroll
    for (int mt = 0; mt < 2; ++mt) {
#pragma unroll
      for (int i = 0; i < 4; ++i) {
        const int row = m0 + mt * 16 + kg * 4 + i;
        qp[(size_t)row * D_ + col] = fexp2(acc[mt][i] * TWOLOG2E);
      }
    }
  }
}

// ---------------- Kernel 2: fused tanh-score + softmax + PV ----------------
// qp holds Eq = e^{2 qproj}; kpbT holds Ek = e^{2(kproj+b1)}.
// 1024 threads = 16 waves, 4 q-rows/block, 1-D grid of 256 blocks.
// XCD swizzle: b = bid & 7. Coalesced float2 kpbT loads (R3's gather
// compaction regressed -6 us: uncoalesced VMEM > VALU saving -> reverted).
// Phase 1 uses 8-way rcp pairing along h (oct_term): 1 v_rcp per 8 elems,
// cutting the quarter-rate trans-pipe issue that dominates this phase.
__global__ __launch_bounds__(1024) void attn_kernel(
    const float* __restrict__ qp, const float* __restrict__ kpbT,
    const float* __restrict__ value, const int* __restrict__ mask,
    const float* __restrict__ w2,
    float* __restrict__ out_vec, float* __restrict__ out_w) {
  __shared__ float smem_p[16 * 512];  // phase1: [w][q(4)][128 k]; phase3: [kq][q][512 col]  32 KB
  __shared__ float pw[4 * 256];       // final weights [q][k]   4 KB
  const int bid = blockIdx.x;
  const int b = bid & 7;               // XCD-local batch
  const int q0 = (bid >> 3) * 4;       // q-chunk
  const int t = threadIdx.x;
  const int lane = t & 63;
  const int w = __builtin_amdgcn_readfirstlane(t >> 6);  // 0..15
  const int kc = w & 1;
  const int hq = w >> 1;
  const int h0 = hq * 64;

  // ---- phase 1: partials over this wave's (128 k, 64 h)
  {
    const float* pk = kpbT + ((size_t)b * D_ + h0) * K_ + kc * 128 + 2 * lane;
    const float* q_0 = qp + (size_t)(b * Q_ + q0 + 0) * D_ + h0;
    const float* q_1 = qp + (size_t)(b * Q_ + q0 + 1) * D_ + h0;
    const float* q_2 = qp + (size_t)(b * Q_ + q0 + 2) * D_ + h0;
    const float* q_3 = qp + (size_t)(b * Q_ + q0 + 3) * D_ + h0;
    const float* w2h = w2 + h0;

    float2 a0 = {0.f, 0.f}, a1 = {0.f, 0.f}, a2 = {0.f, 0.f}, a3 = {0.f, 0.f};
    for (int h = 0; h < 64; h += 8) {
      float2 kv[8];
#pragma unroll
      for (int j = 0; j < 8; ++j) kv[j] = *(const float2*)&pk[(size_t)(h + j) * K_];
      float4 e0a = *(const float4*)(q_0 + h), e0b = *(const float4*)(q_0 + h + 4);
      float4 e1a = *(const float4*)(q_1 + h), e1b = *(const float4*)(q_1 + h + 4);
      float4 e2a = *(const float4*)(q_2 + h), e2b = *(const float4*)(q_2 + h + 4);
      float4 e3a = *(const float4*)(q_3 + h), e3b = *(const float4*)(q_3 + h + 4);
      float4 wa = *(const float4*)(w2h + h), wb = *(const float4*)(w2h + h + 4);
      float E0[8] = {e0a.x, e0a.y, e0a.z, e0a.w, e0b.x, e0b.y, e0b.z, e0b.w};
      float E1[8] = {e1a.x, e1a.y, e1a.z, e1a.w, e1b.x, e1b.y, e1b.z, e1b.w};
      float E2[8] = {e2a.x, e2a.y, e2a.z, e2a.w, e2b.x, e2b.y, e2b.z, e2b.w};
      float E3[8] = {e3a.x, e3a.y, e3a.z, e3a.w, e3b.x, e3b.y, e3b.z, e3b.w};
      float WV[8] = {wa.x, wa.y, wa.z, wa.w, wb.x, wb.y, wb.z, wb.w};
      float Kx[8], Ky[8];
#pragma unroll
      for (int j = 0; j < 8; ++j) { Kx[j] = kv[j].x; Ky[j] = kv[j].y; }
      a0.x += oct_term(E0, Kx, WV); a0.y += oct_term(E0, Ky, WV);
      a1.x += oct_term(E1, Kx, WV); a1.y += oct_term(E1, Ky, WV);
      a2.x += oct_term(E2, Kx, WV); a2.y += oct_term(E2, Ky, WV);
      a3.x += oct_term(E3, Kx, WV); a3.y += oct_term(E3, Ky, WV);
    }
    *(float2*)&smem_p[w * 512 + 0 * 128 + 2 * lane] = a0;
    *(float2*)&smem_p[w * 512 + 1 * 128 + 2 * lane] = a1;
    *(float2*)&smem_p[w * 512 + 2 * 128 + 2 * lane] = a2;
    *(float2*)&smem_p[w * 512 + 3 * 128 + 2 * lane] = a3;
  }
  __syncthreads();

  // ---- phase 2: combine + softmax; wave q (0..3) handles row q0+q
  if (w < 4) {
    const int q = w;
    float sw = 0.f;
#pragma unroll
    for (int m = 0; m < 8; ++m) sw += w2[lane + 64 * m];
#pragma unroll
    for (int off = 32; off; off >>= 1) sw += __shfl_xor(sw, off);

    float s[4];
#pragma unroll
    for (int r = 0; r < 4; ++r) {  // k = r*64 + lane
      const int kcc = r >> 1;
      const int off = (r & 1) * 64 + lane;  // position within kc's 128-range
      float p = 0.f;
#pragma unroll
      for (int hh = 0; hh < 8; ++hh)
        p += smem_p[(hh * 2 + kcc) * 512 + q * 128 + off];
      const int mk = mask[b * K_ + r * 64 + lane];
      s[r] = mk ? MASKVAL : fmaf(-2.f, p, sw) * SCALE;
    }
    float mx = fmaxf(fmaxf(s[0], s[1]), fmaxf(s[2], s[3]));
#pragma unroll
    for (int off = 32; off; off >>= 1) mx = fmaxf(mx, __shfl_xor(mx, off));
    float e[4], sum = 0.f;
#pragma unroll
    for (int r = 0; r < 4; ++r) {
      e[r] = fexp2((s[r] - mx) * L2E);
      sum += e[r];
    }
#pragma unroll
    for (int off = 32; off; off >>= 1) sum += __shfl_xor(sum, off);
    const float inv = frcp(sum);
    float* ow = out_w + (size_t)(b * Q_ + q0 + q) * K_;
#pragma unroll
    for (int r = 0; r < 4; ++r) {
      const float p = e[r] * inv;
      pw[q * 256 + r * 64 + lane] = p;
      ow[r * 64 + lane] = p;
    }
  }
  __syncthreads();

  // ---- phase 3: PV, k-split.
  // thread t: col pair c={2cp,2cp+1}, cp = t&255; k-quarter kq = t>>8 (wave-uniform).
  // Partials for all 4 q rows over 64 k; value[b] read exactly once per block.
  {
    const int cp = t & 255;
    const int col = cp * 2;
    const int kq = t >> 8;  // 0..3, constant within a wave
    const float* vb = value + (size_t)b * K_ * D_ + (size_t)(kq * 64) * D_ + col;
    const float* pwq = pw + kq * 64;

    float2 o0 = {0.f, 0.f}, o1 = {0.f, 0.f}, o2 = {0.f, 0.f}, o3 = {0.f, 0.f};
    for (int k0 = 0; k0 < 64; k0 += 4) {
      const float4 P0 = *(const float4*)&pwq[0 * 256 + k0];  // ds_read_b128, broadcast
      const float4 P1 = *(const float4*)&pwq[1 * 256 + k0];
      const float4 P2 = *(const float4*)&pwq[2 * 256 + k0];
      const float4 P3 = *(const float4*)&pwq[3 * 256 + k0];
      const float2 v0 = *(const float2*)&vb[(size_t)(k0 + 0) * D_];
      const float2 v1 = *(const float2*)&vb[(size_t)(k0 + 1) * D_];
      const float2 v2 = *(const float2*)&vb[(size_t)(k0 + 2) * D_];
      const float2 v3 = *(const float2*)&vb[(size_t)(k0 + 3) * D_];
      o0.x = fmaf(P0.x, v0.x, fmaf(P0.y, v1.x, fmaf(P0.z, v2.x, fmaf(P0.w, v3.x, o0.x))));
      o0.y = fmaf(P0.x, v0.y, fmaf(P0.y, v1.y, fmaf(P0.z, v2.y, fmaf(P0.w, v3.y, o0.y))));
      o1.x = fmaf(P1.x, v0.x, fmaf(P1.y, v1.x, fmaf(P1.z, v2.x, fmaf(P1.w, v3.x, o1.x))));
      o1.y = fmaf(P1.x, v0.y, fmaf(P1.y, v1.y, fmaf(P1.z, v2.y, fmaf(P1.w, v3.y, o1.y))));
      o2.x = fmaf(P2.x, v0.x, fmaf(P2.y, v1.x, fmaf(P2.z, v2.x, fmaf(P2.w, v3.x, o2.x))));
      o2.y = fmaf(P2.x, v0.y, fmaf(P2.y, v1.y, fmaf(P2.z, v2.y, fmaf(P2.w, v3.y, o2.y))));
      o3.x = fmaf(P3.x, v0.x, fmaf(P3.y, v1.x, fmaf(P3.z, v2.x, fmaf(P3.w, v3.x, o3.x))));
      o3.y = fmaf(P3.x, v0.y, fmaf(P3.y, v1.y, fmaf(P3.z, v2.y, fmaf(P3.w, v3.y, o3.y))));
    }
    __syncthreads();  // smem_p phase-2 reads done; safe to overwrite
    // partial layout: smem_p[kq][q][col] = kq*2048 + q*512 + col
    *(float2*)&smem_p[kq * 2048 + 0 * 512 + col] = o0;
    *(float2*)&smem_p[kq * 2048 + 1 * 512 + col] = o1;
    *(float2*)&smem_p[kq * 2048 + 2 * 512 + col] = o2;
    *(float2*)&smem_p[kq * 2048 + 3 * 512 + col] = o3;
  }
  __syncthreads();

  // ---- final reduce: 2048 outputs (4 q x 512 col), 2 per thread
  {
#pragma unroll
    for (int rep = 0; rep < 2; ++rep) {
      const int idx = t + rep * 1024;
      const int q = idx >> 9;
      const int c = idx & 511;
      const float s = smem_p[0 * 2048 + q * 512 + c] + smem_p[1 * 2048 + q * 512 + c] +
                      smem_p[2 * 2048 + q * 512 + c] + smem_p[3 * 2048 + q * 512 + c];
      out_vec[(size_t)(b * Q_ + q0 + q) * D_ + c] = s;
    }
  }
}

extern "C" void kernel_launch(void* const* d_in, const int* in_sizes, int n_in,
                              void* d_out, int out_size, void* d_ws, size_t ws_size,
                              hipStream_t stream) {
  const float* query = (const float*)d_in[0];
  const float* key   = (const float*)d_in[1];
  const float* value = (const float*)d_in[2];
  const int*   mask  = (const int*)d_in[3];
  const float* W1    = (const float*)d_in[4];
  const float* b1    = (const float*)d_in[5];
  const float* w2    = (const float*)d_in[6];

  float* out_vec = (float*)d_out;                   // (8,128,512)
  float* out_w   = out_vec + (size_t)B_ * Q_ * D_;  // (8,128,256)

  float* qp   = (float*)d_ws;                       // 2 MB fp32 Eq [b][q][h]
  float* kpbT = qp + (size_t)B_ * Q_ * D_;          // 4 MB fp32 Ek [b][h][k]

  gemm_kernel<<<dim3(8, 96), 256, 0, stream>>>(query, key, W1, b1, qp, kpbT);
  attn_kernel<<<dim3(256), 1024, 0, stream>>>(qp, kpbT, value, mask, w2,
                                              out_vec, out_w);
}